// Round 10
// baseline (302.368 us; speedup 1.0000x reference)
//
#include <hip/hip_runtime.h>
#include <hip/hip_bf16.h>
#include <math.h>

// MagNet round 10 (= round 4-9 resubmit; six infra failures, audit re-passed):
// fused (aggregation + transform + crelu) layer kernel.
// BM=32, BN=128(full F), BK=32, 256 thr (4 waves), dbuf B via global_load_lds,
// reg-staged A (L fp32 -> bf16 hi/lo split in VALU), stage-2 vs W from L2.
#define B_SZ   32
#define N_SZ   512
#define F_SZ   128

typedef __attribute__((ext_vector_type(8))) short short8v;
typedef __attribute__((ext_vector_type(4))) short short4v;
typedef __attribute__((ext_vector_type(4))) float f32x4;

typedef const __attribute__((address_space(1))) unsigned int* gas1_t;
typedef __attribute__((address_space(3))) unsigned int* las3_t;
#define GLD16(gsrc, ldst) __builtin_amdgcn_global_load_lds( \
    (gas1_t)(const void*)(gsrc), (las3_t)(unsigned int)(size_t)(void*)(ldst), 16, 0, 0)

#define MFMA16(a, bb, c) __builtin_amdgcn_mfma_f32_16x16x32_bf16((a), (bb), (c), 0, 0, 0)

__device__ __forceinline__ short bfh(float v) {
    __hip_bfloat16 h = __float2bfloat16(v);   // RN
    return __builtin_bit_cast(short, h);
}
__device__ __forceinline__ float bf2f(short s) {
    unsigned u = ((unsigned)(unsigned short)s) << 16;
    return __builtin_bit_cast(float, u);
}
__device__ __forceinline__ void split1(float v, short& h, short& l) {
    short hs = bfh(v);
    h = hs;
    l = bfh(v - bf2f(hs));
}
__device__ __forceinline__ void splitpack(const float4& a, const float4& b,
                                          short8v& h, short8v& l) {
    const float va[8] = {a.x, a.y, a.z, a.w, b.x, b.y, b.z, b.w};
    #pragma unroll
    for (int j = 0; j < 8; ++j) {
        short hs, ls;
        split1(va[j], hs, ls);
        h[j] = hs; l[j] = ls;
    }
}

// ---------------------------------------------------------------------------
// Fused layer: h_out = crelu( (L @ h_in) @ W )   all complex, bf16x3.
// h_in: transposed bf16 planes [B][128 f][512 node] (rh,rl[,ih,il]).
// W planes: [128 out][128 f] per layer. h_out: same layout as h_in (4 planes).
// Grid (16 row-blocks, 32 batches), 256 threads = 4 waves (wn = wave id).
// ---------------------------------------------------------------------------
template<int HAS_BIM>
__global__ __launch_bounds__(256, 2)
void fused_layer(const float* __restrict__ Lre, const float* __restrict__ Lim,
                 const short* __restrict__ Brh, const short* __restrict__ Brl,
                 const short* __restrict__ Bih, const short* __restrict__ Bil,
                 const short* __restrict__ Wrh, const short* __restrict__ Wrl,
                 const short* __restrict__ Wih, const short* __restrict__ Wil,
                 short* __restrict__ Orh, short* __restrict__ Orl,
                 short* __restrict__ Oih, short* __restrict__ Oil)
{
    __shared__ __align__(16) char ldsraw[65536];          // 64 KB -> 2 blocks/CU
    short (*Bs)[4][4096] = (short(*)[4][4096])ldsraw;     // [buf][plane][n*32+8*slot]
    short (*Ts)[32 * 136] = (short(*)[32 * 136])ldsraw;   // [plane][node*136+f] (34.8KB)

    const int t = threadIdx.x;
    // XCD-bijective remap: each XCD gets 4 whole batches (512 = 8*64).
    const int lid = blockIdx.y * 16 + blockIdx.x;
    const int nl = (lid & 7) * 64 + (lid >> 3);
    const int b = nl >> 4;
    const int rowBase = (nl & 15) * 32;

    const float* pLre = Lre + (long)b * (N_SZ * N_SZ);
    const float* pLim = Lim + (long)b * (N_SZ * N_SZ);
    const long sB = (long)F_SZ * N_SZ;
    const short* pBrh = Brh + (long)b * sB;
    const short* pBrl = Brl + (long)b * sB;
    const short* pBih = HAS_BIM ? (Bih + (long)b * sB) : nullptr;
    const short* pBil = HAS_BIM ? (Bil + (long)b * sB) : nullptr;

    const int wn = t >> 6;                  // wave 0..3 -> F cols 32*wn
    const int l = t & 63;
    const int r16 = l & 15, g = l >> 4;

    short8v SGN;
    #pragma unroll
    for (int j = 0; j < 8; ++j) SGN[j] = (short)0x8000;

    const f32x4 z4 = {0.f, 0.f, 0.f, 0.f};
    f32x4 accR[2][2], accI[2][2];
    #pragma unroll
    for (int i = 0; i < 2; ++i)
        #pragma unroll
        for (int j = 0; j < 2; ++j) { accR[i][j] = z4; accI[i][j] = z4; }

    // ---- staging helpers -------------------------------------------------
#define STAGE_B(buf, kb)                                                     \
    {                                                                        \
        _Pragma("unroll")                                                    \
        for (int rep = 0; rep < 2; ++rep) {                                  \
            const int i_ = t + rep * 256;                                    \
            const int n_ = i_ >> 2, s_ = i_ & 3;                             \
            const int c_ = s_ ^ ((n_ >> 1) & 3);                             \
            const long so_ = (long)n_ * 512 + (kb) + 8 * c_;                 \
            GLD16(pBrh + so_, &Bs[buf][0][i_ * 8]);                          \
            GLD16(pBrl + so_, &Bs[buf][1][i_ * 8]);                          \
            if (HAS_BIM) {                                                   \
                GLD16(pBih + so_, &Bs[buf][2][i_ * 8]);                      \
                GLD16(pBil + so_, &Bs[buf][3][i_ * 8]);                      \
            }                                                                \
        }                                                                    \
    }

#define LOAD_A(R, kb)                                                        \
    {                                                                        \
        _Pragma("unroll")                                                    \
        for (int tm_ = 0; tm_ < 2; ++tm_) {                                  \
            const long ro_ = (long)(rowBase + tm_ * 16 + r16) * 512 + (kb) + g * 8; \
            R[tm_][0][0] = *(const float4*)(pLre + ro_);                     \
            R[tm_][0][1] = *(const float4*)(pLre + ro_ + 4);                 \
            R[tm_][1][0] = *(const float4*)(pLim + ro_);                     \
            R[tm_][1][1] = *(const float4*)(pLim + ro_ + 4);                 \
        }                                                                    \
    }

#define STEP(buf, R)                                                         \
    {                                                                        \
        short8v FA[2][4];                                                    \
        _Pragma("unroll")                                                    \
        for (int tm_ = 0; tm_ < 2; ++tm_) {                                  \
            splitpack(R[tm_][0][0], R[tm_][0][1], FA[tm_][0], FA[tm_][1]);   \
            splitpack(R[tm_][1][0], R[tm_][1][1], FA[tm_][2], FA[tm_][3]);   \
        }                                                                    \
        short8v fB[2][4];                                                    \
        _Pragma("unroll")                                                    \
        for (int tn_ = 0; tn_ < 2; ++tn_) {                                  \
            const int n_ = wn * 32 + tn_ * 16 + r16;                         \
            const int off_ = n_ * 32 + 8 * (g ^ ((n_ >> 1) & 3));            \
            fB[tn_][0] = *(const short8v*)&Bs[buf][0][off_];                 \
            fB[tn_][1] = *(const short8v*)&Bs[buf][1][off_];                 \
            if (HAS_BIM) {                                                   \
                fB[tn_][2] = *(const short8v*)&Bs[buf][2][off_];             \
                fB[tn_][3] = *(const short8v*)&Bs[buf][3][off_];             \
            }                                                                \
        }                                                                    \
        _Pragma("unroll")                                                    \
        for (int tm_ = 0; tm_ < 2; ++tm_) {                                  \
            const short8v nIh_ = FA[tm_][2] ^ SGN;                           \
            const short8v nIl_ = FA[tm_][3] ^ SGN;                           \
            _Pragma("unroll")                                                \
            for (int tn_ = 0; tn_ < 2; ++tn_) {                              \
                accR[tm_][tn_] = MFMA16(FA[tm_][0], fB[tn_][0], accR[tm_][tn_]); \
                accR[tm_][tn_] = MFMA16(FA[tm_][1], fB[tn_][0], accR[tm_][tn_]); \
                accR[tm_][tn_] = MFMA16(FA[tm_][0], fB[tn_][1], accR[tm_][tn_]); \
                accI[tm_][tn_] = MFMA16(FA[tm_][2], fB[tn_][0], accI[tm_][tn_]); \
                accI[tm_][tn_] = MFMA16(FA[tm_][3], fB[tn_][0], accI[tm_][tn_]); \
                accI[tm_][tn_] = MFMA16(FA[tm_][2], fB[tn_][1], accI[tm_][tn_]); \
                if (HAS_BIM) {                                               \
                    accR[tm_][tn_] = MFMA16(nIh_, fB[tn_][2], accR[tm_][tn_]);   \
                    accR[tm_][tn_] = MFMA16(nIl_, fB[tn_][2], accR[tm_][tn_]);   \
                    accR[tm_][tn_] = MFMA16(nIh_, fB[tn_][3], accR[tm_][tn_]);   \
                    accI[tm_][tn_] = MFMA16(FA[tm_][0], fB[tn_][2], accI[tm_][tn_]); \
                    accI[tm_][tn_] = MFMA16(FA[tm_][1], fB[tn_][2], accI[tm_][tn_]); \
                    accI[tm_][tn_] = MFMA16(FA[tm_][0], fB[tn_][3], accI[tm_][tn_]); \
                }                                                            \
            }                                                                \
        }                                                                    \
    }

    // ---- stage 1: T = L @ h, prefetch-pipelined --------------------------
    float4 Ra[2][2][2], Rb[2][2][2];
    STAGE_B(0, 0);
    LOAD_A(Ra, 0);
    __syncthreads();            // drains vmcnt(0): buf0 + Ra ready

    for (int k2 = 0; k2 < 8; ++k2) {
        const int kb = k2 * 64;
        STAGE_B(1, kb + 32);    // prefetch odd step
        LOAD_A(Rb, kb + 32);
        STEP(0, Ra);            // compute even step
        __syncthreads();        // drains: buf1 + Rb ready
        if (k2 < 7) {
            STAGE_B(0, kb + 64);
            LOAD_A(Ra, kb + 64);
        }
        STEP(1, Rb);
        __syncthreads();
    }

    // ---- T tile -> LDS planes (overlay; loop-end barrier made Bs dead) ---
    #pragma unroll
    for (int tm = 0; tm < 2; ++tm)
        #pragma unroll
        for (int tn = 0; tn < 2; ++tn) {
            const int f = wn * 32 + tn * 16 + r16;
            #pragma unroll
            for (int rr = 0; rr < 4; ++rr) {
                const int node = tm * 16 + 4 * g + rr;
                short hs, ls;
                split1(accR[tm][tn][rr], hs, ls);
                Ts[0][node * 136 + f] = hs; Ts[1][node * 136 + f] = ls;
                split1(accI[tm][tn][rr], hs, ls);
                Ts[2][node * 136 + f] = hs; Ts[3][node * 136 + f] = ls;
            }
        }
    __syncthreads();

    // ---- stage 2: h' = crelu(T @ W) --------------------------------------
    f32x4 acc2R[2][2], acc2I[2][2];
    #pragma unroll
    for (int i = 0; i < 2; ++i)
        #pragma unroll
        for (int j = 0; j < 2; ++j) { acc2R[i][j] = z4; acc2I[i][j] = z4; }

    #pragma unroll
    for (int c = 0; c < 4; ++c) {
        short8v fW[2][4];
        #pragma unroll
        for (int tn = 0; tn < 2; ++tn) {
            const long wo = (long)(wn * 32 + tn * 16 + r16) * 128 + c * 32 + g * 8;
            fW[tn][0] = *(const short8v*)(Wrh + wo);
            fW[tn][1] = *(const short8v*)(Wrl + wo);
            fW[tn][2] = *(const short8v*)(Wih + wo);
            fW[tn][3] = *(const short8v*)(Wil + wo);
        }
        short8v fT[2][4];
        #pragma unroll
        for (int tm = 0; tm < 2; ++tm) {
            const int off = (tm * 16 + r16) * 136 + c * 32 + g * 8;
            #pragma unroll
            for (int p = 0; p < 4; ++p)
                fT[tm][p] = *(const short8v*)&Ts[p][off];
        }
        #pragma unroll
        for (int tm = 0; tm < 2; ++tm) {
            const short8v nIh = fT[tm][2] ^ SGN;
            const short8v nIl = fT[tm][3] ^ SGN;
            #pragma unroll
            for (int tn = 0; tn < 2; ++tn) {
                acc2R[tm][tn] = MFMA16(fT[tm][0], fW[tn][0], acc2R[tm][tn]);
                acc2R[tm][tn] = MFMA16(fT[tm][1], fW[tn][0], acc2R[tm][tn]);
                acc2R[tm][tn] = MFMA16(fT[tm][0], fW[tn][1], acc2R[tm][tn]);
                acc2R[tm][tn] = MFMA16(nIh, fW[tn][2], acc2R[tm][tn]);
                acc2R[tm][tn] = MFMA16(nIl, fW[tn][2], acc2R[tm][tn]);
                acc2R[tm][tn] = MFMA16(nIh, fW[tn][3], acc2R[tm][tn]);
                acc2I[tm][tn] = MFMA16(fT[tm][2], fW[tn][0], acc2I[tm][tn]);
                acc2I[tm][tn] = MFMA16(fT[tm][3], fW[tn][0], acc2I[tm][tn]);
                acc2I[tm][tn] = MFMA16(fT[tm][2], fW[tn][1], acc2I[tm][tn]);
                acc2I[tm][tn] = MFMA16(fT[tm][0], fW[tn][2], acc2I[tm][tn]);
                acc2I[tm][tn] = MFMA16(fT[tm][1], fW[tn][2], acc2I[tm][tn]);
                acc2I[tm][tn] = MFMA16(fT[tm][0], fW[tn][3], acc2I[tm][tn]);
            }
        }
    }

    // ---- epilogue: crelu, split, transposed short4v stores ---------------
    #pragma unroll
    for (int tm = 0; tm < 2; ++tm)
        #pragma unroll
        for (int tn = 0; tn < 2; ++tn) {
            const int out = wn * 32 + tn * 16 + r16;
            const int node0 = rowBase + tm * 16 + 4 * g;
            short4v rh, rl, ih, il;
            #pragma unroll
            for (int rr = 0; rr < 4; ++rr) {
                float cr = acc2R[tm][tn][rr], ci = acc2I[tm][tn][rr];
                if (cr < 0.f) { cr = 0.f; ci = 0.f; }
                short hs, ls;
                split1(cr, hs, ls); rh[rr] = hs; rl[rr] = ls;
                split1(ci, hs, ls); ih[rr] = hs; il[rr] = ls;
            }
            const long base = ((long)b * 128 + out) * 512 + node0;
            *(short4v*)(Orh + base) = rh;
            *(short4v*)(Orl + base) = rl;
            *(short4v*)(Oih + base) = ih;
            *(short4v*)(Oil + base) = il;
        }
#undef STAGE_B
#undef LOAD_A
#undef STEP
}

// x [B,512,128] fp32 -> transposed bf16 planes x^T [B,128,512] hi/lo
__global__ __launch_bounds__(256)
void split_x_kernel(const float* __restrict__ x, short* __restrict__ Xh,
                    short* __restrict__ Xl)
{
    __shared__ float XT[128][65];
    const int b = blockIdx.x >> 3, nc = blockIdx.x & 7;
    const int t = threadIdx.x;
    {
        const int nlan = t & 63, fc = t >> 6;
        const float* src = x + ((long)b * 512 + nc * 64 + nlan) * 128 + fc * 32;
        #pragma unroll
        for (int q = 0; q < 8; ++q) {
            float4 v = *(const float4*)(src + q * 4);
            XT[fc * 32 + q * 4 + 0][nlan] = v.x;
            XT[fc * 32 + q * 4 + 1][nlan] = v.y;
            XT[fc * 32 + q * 4 + 2][nlan] = v.z;
            XT[fc * 32 + q * 4 + 3][nlan] = v.w;
        }
    }
    __syncthreads();
    const int f = t >> 1, half = t & 1;
    short8v H[4], L[4];
    #pragma unroll
    for (int i = 0; i < 32; ++i) {
        short hs, ls;
        split1(XT[f][half * 32 + i], hs, ls);
        H[i >> 3][i & 7] = hs;
        L[i >> 3][i & 7] = ls;
    }
    const long base = ((long)b * 128 + f) * 512 + nc * 64 + half * 32;
    #pragma unroll
    for (int q = 0; q < 4; ++q) {
        *(short8v*)(Xh + base + q * 8) = H[q];
        *(short8v*)(Xl + base + q * 8) = L[q];
    }
}

// W [3,128,128] fp32 re/im -> transposed planes W^T [3,128 out,128 k] x4
__global__ __launch_bounds__(128)
void split_w_kernel(const float* __restrict__ Wr, const float* __restrict__ Wi,
                    short* __restrict__ Wrh, short* __restrict__ Wrl,
                    short* __restrict__ Wih, short* __restrict__ Wil)
{
    const int layer = blockIdx.x >> 7, n = blockIdx.x & 127;
    const int k = threadIdx.x;
    const long src = ((long)layer * 128 + k) * 128 + n;
    const long dst = ((long)layer * 128 + n) * 128 + k;
    short hs, ls;
    split1(Wr[src], hs, ls); Wrh[dst] = hs; Wrl[dst] = ls;
    split1(Wi[src], hs, ls); Wih[dst] = hs; Wil[dst] = ls;
}

// partial mean over 64 nodes: part[b*8+nc][256]
__global__ __launch_bounds__(256)
void readout_kernel(const short* __restrict__ Hrh, const short* __restrict__ Hrl,
                    const short* __restrict__ Hih, const short* __restrict__ Hil,
                    float* __restrict__ part)
{
    const int b = blockIdx.x >> 3, nc = blockIdx.x & 7;
    const int t = threadIdx.x;
    const int f = t & 127;
    const short* Ph = (t < 128) ? Hrh : Hih;
    const short* Pl = (t < 128) ? Hrl : Hil;
    const long base = ((long)b * 128 + f) * 512 + nc * 64;
    float s = 0.f;
    #pragma unroll
    for (int q = 0; q < 8; ++q) {
        short8v vh = *(const short8v*)(Ph + base + q * 8);
        short8v vl = *(const short8v*)(Pl + base + q * 8);
        #pragma unroll
        for (int j = 0; j < 8; ++j) s += bf2f(vh[j]) + bf2f(vl[j]);
    }
    part[((long)b * 8 + nc) * 256 + t] = s;
}

// fc1+relu -> fc2 -> softmax (one block per batch row)
__global__ __launch_bounds__(256)
void head_kernel(const float* __restrict__ part,
                 const float* __restrict__ w1, const float* __restrict__ b1,
                 const float* __restrict__ w2, const float* __restrict__ b2,
                 float* __restrict__ out)
{
    __shared__ float sf[256];
    __shared__ float sz[256];
    __shared__ float sl[16];
    const int b = blockIdx.x;
    const int t = threadIdx.x;

    float s = 0.f;
    #pragma unroll
    for (int nc = 0; nc < 8; ++nc) s += part[((long)b * 8 + nc) * 256 + t];
    sf[t] = s * (1.0f / 512.0f);
    __syncthreads();

    float acc = b1[t];
    const float* wrow = w1 + (long)t * 256;
    #pragma unroll 8
    for (int j = 0; j < 256; ++j) acc = fmaf(sf[j], wrow[j], acc);
    sz[t] = fmaxf(acc, 0.f);
    __syncthreads();

    if (t < 10) {
        float lg = b2[t];
        const float* w2r = w2 + (long)t * 256;
        #pragma unroll 8
        for (int j = 0; j < 256; ++j) lg = fmaf(sz[j], w2r[j], lg);
        sl[t] = lg;
    }
    __syncthreads();
    if (t == 0) {
        float m = sl[0];
        for (int c = 1; c < 10; ++c) m = fmaxf(m, sl[c]);
        float e[10]; float ss = 0.f;
        for (int c = 0; c < 10; ++c) { e[c] = expf(sl[c] - m); ss += e[c]; }
        const float inv = 1.f / ss;
        for (int c = 0; c < 10; ++c) out[b * 10 + c] = e[c] * inv;
    }
}

extern "C" void kernel_launch(void* const* d_in, const int* in_sizes, int n_in,
                              void* d_out, int out_size, void* d_ws, size_t ws_size,
                              hipStream_t stream)
{
    const float* x     = (const float*)d_in[0];   // [32,512,128]
    const float* Lre   = (const float*)d_in[1];   // [32,512,512]
    const float* Lim   = (const float*)d_in[2];
    const float* Wr    = (const float*)d_in[3];   // [3,128,128]
    const float* Wi    = (const float*)d_in[4];
    const float* fc1_w = (const float*)d_in[5];
    const float* fc1_b = (const float*)d_in[6];
    const float* fc2_w = (const float*)d_in[7];
    const float* fc2_b = (const float*)d_in[8];
    float* out = (float*)d_out;

    const long BNF = (long)B_SZ * N_SZ * F_SZ;    // 2,097,152
    // h ping-pong: 2 sets of 4 transposed bf16 planes
    short* h0 = (short*)d_ws;                     // [4][BNF]
    short* h1 = h0 + 4 * BNF;
    short* Wrh = h1 + 4 * BNF;                    // [3][128][128] planes
    short* Wrl = Wrh + 3 * 128 * 128;
    short* Wih = Wrl + 3 * 128 * 128;
    short* Wil = Wih + 3 * 128 * 128;
    float* part = (float*)(Wil + 3 * 128 * 128);  // [32*8][256]

    const dim3 ggrid(16, 32);
    const long wsz = 128 * 128;

    split_w_kernel<<<384, 128, 0, stream>>>(Wr, Wi, Wrh, Wrl, Wih, Wil);
    split_x_kernel<<<256, 256, 0, stream>>>(x, h0, h0 + BNF);

    // layer 0: h0(real planes) -> h1
    fused_layer<0><<<ggrid, 256, 0, stream>>>(
        Lre, Lim, h0, h0 + BNF, nullptr, nullptr,
        Wrh, Wrl, Wih, Wil,
        h1, h1 + BNF, h1 + 2 * BNF, h1 + 3 * BNF);
    // layer 1: h1 -> h0
    fused_layer<1><<<ggrid, 256, 0, stream>>>(
        Lre, Lim, h1, h1 + BNF, h1 + 2 * BNF, h1 + 3 * BNF,
        Wrh + wsz, Wrl + wsz, Wih + wsz, Wil + wsz,
        h0, h0 + BNF, h0 + 2 * BNF, h0 + 3 * BNF);
    // layer 2: h0 -> h1
    fused_layer<1><<<ggrid, 256, 0, stream>>>(
        Lre, Lim, h0, h0 + BNF, h0 + 2 * BNF, h0 + 3 * BNF,
        Wrh + 2 * wsz, Wrl + 2 * wsz, Wih + 2 * wsz, Wil + 2 * wsz,
        h1, h1 + BNF, h1 + 2 * BNF, h1 + 3 * BNF);

    readout_kernel<<<256, 256, 0, stream>>>(
        h1, h1 + BNF, h1 + 2 * BNF, h1 + 3 * BNF, part);
    head_kernel<<<32, 256, 0, stream>>>(part, fc1_w, fc1_b, fc2_w, fc2_b, out);
}